// Round 4
// baseline (1338.671 us; speedup 1.0000x reference)
//
#include <hip/hip_runtime.h>
#include <math.h>

// Problem constants
#define BB 2
#define SS 2048
#define EE 2048
#define HH 16
#define KVH 4
#define HD 128

typedef __attribute__((ext_vector_type(8))) short short8;
typedef __attribute__((ext_vector_type(4))) float f32x4;

__device__ __forceinline__ short f2b(float f) {
  unsigned u = __float_as_uint(f);
  unsigned r = (u + 0x7fffu + ((u >> 16) & 1u)) >> 16;
  return (short)r;
}

// RoPE freq replicating reference fp32 overflow: freqs[jp] = 1/theta^(2jp);
// theta^8 = 1e40 -> inf -> 0 (exp2f underflows likewise; jp>=4 angles are
// <=1e-37 -> rotation indistinguishable from identity at bf16 precision).
__device__ __forceinline__ float rope_freq(int jp) {
  return exp2f(-(float)(2 * jp) * 16.609640474436812f);
}

// ---------------- weight transpose + f32->bf16: (K,N) f32 -> (N,K) bf16 ----
__global__ void transpose_f2b(const float* __restrict__ in, short* __restrict__ out,
                              int K, int N) {
  __shared__ short tile[32][33];
  int n0 = blockIdx.x * 32, k0 = blockIdx.y * 32;
  int tx = threadIdx.x, ty = threadIdx.y;  // 32 x 8
#pragma unroll
  for (int i = 0; i < 32; i += 8)
    tile[ty + i][tx] = f2b(in[(size_t)(k0 + ty + i) * N + n0 + tx]);
  __syncthreads();
#pragma unroll
  for (int i = 0; i < 32; i += 8)
    out[(size_t)(n0 + ty + i) * K + k0 + tx] = tile[tx][ty + i];
}

// -------------------- QKV GEMM + bias + RoPE --------------------
// A: x (4096 x 2048) f32 row-major. Bt: packed bf16 [wq^T; wk^T; wv^T] (3072 x 2048).
// 128x128 tile, 4 waves (2x2 of 64x64), K-step 32, mfma 16x16x32 bf16.
__global__ __launch_bounds__(256) void gemm_qkv(
    const float* __restrict__ A, const short* __restrict__ Bt,
    const float* __restrict__ bq, const float* __restrict__ bk,
    const float* __restrict__ bv,
    short* __restrict__ qbuf, short* __restrict__ kbuf, short* __restrict__ vtr) {
  __shared__ __align__(16) short Al[128 * 32];
  __shared__ __align__(16) short Bl[128 * 32];
  const int K = EE;
  int t = threadIdx.x, lane = t & 63, w = t >> 6;
  int wm = (w >> 1) * 64, wn = (w & 1) * 64;
  int m0 = blockIdx.x * 128, n0 = blockIdx.y * 128;
  const float* Ab = A + (size_t)m0 * K;
  const short* Bb = Bt + (size_t)n0 * K;
  int sr = t >> 2, sc = (t & 3) * 8;  // 4 threads per 32-elem row
  f32x4 acc[4][4] = {};
  for (int k0 = 0; k0 < K; k0 += 32) {
    float4 fa0 = *(const float4*)(Ab + (size_t)sr * K + k0 + sc);
    float4 fa1 = *(const float4*)(Ab + (size_t)sr * K + k0 + sc + 4);
    float4 fb0 = *(const float4*)(Ab + (size_t)(64 + sr) * K + k0 + sc);
    float4 fb1 = *(const float4*)(Ab + (size_t)(64 + sr) * K + k0 + sc + 4);
    short8 gb0 = *(const short8*)(Bb + (size_t)sr * K + k0 + sc);
    short8 gb1 = *(const short8*)(Bb + (size_t)(64 + sr) * K + k0 + sc);
    short8 ca0, ca1;
    ca0[0] = f2b(fa0.x); ca0[1] = f2b(fa0.y); ca0[2] = f2b(fa0.z); ca0[3] = f2b(fa0.w);
    ca0[4] = f2b(fa1.x); ca0[5] = f2b(fa1.y); ca0[6] = f2b(fa1.z); ca0[7] = f2b(fa1.w);
    ca1[0] = f2b(fb0.x); ca1[1] = f2b(fb0.y); ca1[2] = f2b(fb0.z); ca1[3] = f2b(fb0.w);
    ca1[4] = f2b(fb1.x); ca1[5] = f2b(fb1.y); ca1[6] = f2b(fb1.z); ca1[7] = f2b(fb1.w);
    *(short8*)&Al[sr * 32 + sc] = ca0;
    *(short8*)&Al[(64 + sr) * 32 + sc] = ca1;
    *(short8*)&Bl[sr * 32 + sc] = gb0;
    *(short8*)&Bl[(64 + sr) * 32 + sc] = gb1;
    __syncthreads();
    short8 a[4], b[4];
#pragma unroll
    for (int i = 0; i < 4; i++)
      a[i] = *(const short8*)&Al[(wm + i * 16 + (lane & 15)) * 32 + (lane >> 4) * 8];
#pragma unroll
    for (int j = 0; j < 4; j++)
      b[j] = *(const short8*)&Bl[(wn + j * 16 + (lane & 15)) * 32 + (lane >> 4) * 8];
#pragma unroll
    for (int i = 0; i < 4; i++)
#pragma unroll
      for (int j = 0; j < 4; j++)
        acc[i][j] = __builtin_amdgcn_mfma_f32_16x16x32_bf16(a[i], b[j], acc[i][j], 0, 0, 0);
    __syncthreads();
  }
  int lj = lane & 15, lr = lane >> 4;
  if (n0 < 2048) {  // ---- Q: bias + rope -> qbuf[(b*S+s)*2048 + n]
#pragma unroll
    for (int j = 0; j < 4; j++) {
      int d = wn + j * 16 + lj;  // within-head dim (one head per 128-tile)
      int n = n0 + d;
      float bias = bq[n];
      float freq = rope_freq(d >> 1);
      bool odd = (d & 1) != 0;
#pragma unroll
      for (int i = 0; i < 4; i++)
#pragma unroll
        for (int r = 0; r < 4; r++) {
          int m = m0 + wm + i * 16 + lr * 4 + r;
          int s = m & (SS - 1);
          float val = acc[i][j][r] + bias;
          float other = __shfl_xor(val, 1, 64);
          float ang = (float)s * freq;
          float cs = cosf(ang), sn = sinf(ang);
          float res = odd ? (other * sn + val * cs) : (val * cs - other * sn);
          qbuf[(size_t)m * 2048 + n] = f2b(res);
        }
    }
  } else if (n0 < 2560) {  // ---- K: bias + rope -> kbuf[((b*KVH+kvh)*S+s)*HD+d]
    int base = n0 - 2048;
    int kvh = base >> 7;
#pragma unroll
    for (int j = 0; j < 4; j++) {
      int d = wn + j * 16 + lj;
      float bias = bk[base + d];
      float freq = rope_freq(d >> 1);
      bool odd = (d & 1) != 0;
#pragma unroll
      for (int i = 0; i < 4; i++)
#pragma unroll
        for (int r = 0; r < 4; r++) {
          int m = m0 + wm + i * 16 + lr * 4 + r;
          int s = m & (SS - 1);
          int b = m >> 11;
          float val = acc[i][j][r] + bias;
          float other = __shfl_xor(val, 1, 64);
          float ang = (float)s * freq;
          float cs = cosf(ang), sn = sinf(ang);
          float res = odd ? (other * sn + val * cs) : (val * cs - other * sn);
          kbuf[((size_t)(b * KVH + kvh) * SS + s) * HD + d] = f2b(res);
        }
    }
  } else {  // ---- V: bias, store transposed -> vtr[((b*KVH+kvh)*HD+d)*S+s]
    int base = n0 - 2560;
    int kvh = base >> 7;
#pragma unroll
    for (int j = 0; j < 4; j++) {
      int d = wn + j * 16 + lj;
      float bias = bv[base + d];
#pragma unroll
      for (int i = 0; i < 4; i++)
#pragma unroll
        for (int r = 0; r < 4; r++) {
          int m = m0 + wm + i * 16 + lr * 4 + r;
          int s = m & (SS - 1);
          int b = m >> 11;
          vtr[((size_t)(b * KVH + kvh) * HD + d) * SS + s] = f2b(acc[i][j][r] + bias);
        }
    }
  }
}

// -------------------- flash attention (causal, GQA) --------------------
// Block: 64 q-rows of one (b,h); 4 waves x 16 rows. K/V tiles of 64 keys.
__global__ __launch_bounds__(256) void attn_kernel(
    const short* __restrict__ qb, const short* __restrict__ kb,
    const short* __restrict__ vt, short* __restrict__ ao) {
  __shared__ __align__(16) short Kl[64 * 128];     // (key, hd)
  __shared__ __align__(16) short Vl[128 * 64];     // (hd, key)
  __shared__ __align__(16) short Pl[4 * 16 * 64];  // per-wave P
  int t = threadIdx.x, lane = t & 63, w = t >> 6;
  int lj = lane & 15, lr = lane >> 4;
  int qt = blockIdx.x, h = blockIdx.y, b = blockIdx.z;
  int kvh = h >> 2;  // REP = 4
  int qb0 = qt * 64;
  const short* qbase = qb + (size_t)(b * SS) * 2048 + h * HD;
  const short* kbase = kb + (size_t)(b * KVH + kvh) * SS * HD;
  const short* vbase = vt + (size_t)(b * KVH + kvh) * HD * SS;
  short8 aq[4];
  int sq = qb0 + w * 16 + lj;
#pragma unroll
  for (int kk = 0; kk < 4; kk++)
    aq[kk] = *(const short8*)(qbase + (size_t)sq * 2048 + kk * 32 + lr * 8);
  f32x4 O[8] = {};
  const float NEG = -1e30f;
  float mrow[4] = {NEG, NEG, NEG, NEG};
  float lrow[4] = {0.f, 0.f, 0.f, 0.f};
  const float scale = 0.088388347648318447f;  // 1/sqrt(128)
  int nkt = qt + 1;
  for (int kt = 0; kt < nkt; ++kt) {
    short8 gk[4], gv[4];
#pragma unroll
    for (int i = 0; i < 4; i++) {
      gk[i] = *(const short8*)(kbase + (size_t)(kt * 64 + i * 16 + (t >> 4)) * HD + (t & 15) * 8);
      gv[i] = *(const short8*)(vbase + (size_t)(i * 32 + (t >> 3)) * SS + kt * 64 + (t & 7) * 8);
    }
#pragma unroll
    for (int i = 0; i < 4; i++) {
      *(short8*)&Kl[(i * 16 + (t >> 4)) * 128 + (t & 15) * 8] = gk[i];
      *(short8*)&Vl[(i * 32 + (t >> 3)) * 64 + (t & 7) * 8] = gv[i];
    }
    __syncthreads();
    f32x4 S[4];
#pragma unroll
    for (int nt = 0; nt < 4; nt++) {
      f32x4 sc = {};
#pragma unroll
      for (int kk = 0; kk < 4; kk++) {
        short8 bk_ = *(const short8*)&Kl[(nt * 16 + lj) * 128 + kk * 32 + lr * 8];
        sc = __builtin_amdgcn_mfma_f32_16x16x32_bf16(aq[kk], bk_, sc, 0, 0, 0);
      }
      S[nt] = sc;
    }
    int rowg = qb0 + w * 16 + lr * 4;
#pragma unroll
    for (int nt = 0; nt < 4; nt++) {
      int colg = kt * 64 + nt * 16 + lj;
#pragma unroll
      for (int r = 0; r < 4; r++) {
        float v = S[nt][r] * scale;
        if (colg > rowg + r) v = NEG;  // finite mask; exp underflows to 0
        S[nt][r] = v;
      }
    }
    float alpha[4];
#pragma unroll
    for (int r = 0; r < 4; r++) {
      float m_ = fmaxf(fmaxf(S[0][r], S[1][r]), fmaxf(S[2][r], S[3][r]));
#pragma unroll
      for (int off = 1; off < 16; off <<= 1) m_ = fmaxf(m_, __shfl_xor(m_, off, 64));
      float mn = fmaxf(mrow[r], m_);
      alpha[r] = __expf(mrow[r] - mn);
      mrow[r] = mn;
    }
    float ls[4] = {0.f, 0.f, 0.f, 0.f};
#pragma unroll
    for (int nt = 0; nt < 4; nt++)
#pragma unroll
      for (int r = 0; r < 4; r++) {
        float p = __expf(S[nt][r] - mrow[r]);
        ls[r] += p;
        Pl[(w * 16 + lr * 4 + r) * 64 + nt * 16 + lj] = f2b(p);
      }
#pragma unroll
    for (int r = 0; r < 4; r++) {
      float s_ = ls[r];
#pragma unroll
      for (int off = 1; off < 16; off <<= 1) s_ += __shfl_xor(s_, off, 64);
      lrow[r] = lrow[r] * alpha[r] + s_;
    }
#pragma unroll
    for (int jt = 0; jt < 8; jt++)
#pragma unroll
      for (int r = 0; r < 4; r++) O[jt][r] *= alpha[r];
#pragma unroll
    for (int kk = 0; kk < 2; kk++) {
      short8 ap = *(const short8*)&Pl[(w * 16 + lj) * 64 + kk * 32 + lr * 8];
#pragma unroll
      for (int jt = 0; jt < 8; jt++) {
        short8 bv_ = *(const short8*)&Vl[(jt * 16 + lj) * 64 + kk * 32 + lr * 8];
        O[jt] = __builtin_amdgcn_mfma_f32_16x16x32_bf16(ap, bv_, O[jt], 0, 0, 0);
      }
    }
    __syncthreads();
  }
  size_t obase = (size_t)(b * SS + qb0 + w * 16) * 2048 + h * HD;
#pragma unroll
  for (int jt = 0; jt < 8; jt++)
#pragma unroll
    for (int r = 0; r < 4; r++) {
      int row = lr * 4 + r;
      ao[obase + (size_t)row * 2048 + jt * 16 + lj] = f2b(O[jt][r] / lrow[r]);
    }
}

// -------------- output projection GEMM + bias (f32 output) --------------
__global__ __launch_bounds__(256) void gemm_out(
    const short* __restrict__ A, const short* __restrict__ Bt,
    const float* __restrict__ bo, float* __restrict__ out) {
  __shared__ __align__(16) short Al[128 * 32];
  __shared__ __align__(16) short Bl[128 * 32];
  const int K = EE;
  int t = threadIdx.x, lane = t & 63, w = t >> 6;
  int wm = (w >> 1) * 64, wn = (w & 1) * 64;
  int m0 = blockIdx.x * 128, n0 = blockIdx.y * 128;
  const short* Ab = A + (size_t)m0 * K;
  const short* Bb = Bt + (size_t)n0 * K;
  int sr = t >> 2, sc = (t & 3) * 8;
  f32x4 acc[4][4] = {};
  for (int k0 = 0; k0 < K; k0 += 32) {
    short8 ga0 = *(const short8*)(Ab + (size_t)sr * K + k0 + sc);
    short8 ga1 = *(const short8*)(Ab + (size_t)(64 + sr) * K + k0 + sc);
    short8 gb0 = *(const short8*)(Bb + (size_t)sr * K + k0 + sc);
    short8 gb1 = *(const short8*)(Bb + (size_t)(64 + sr) * K + k0 + sc);
    *(short8*)&Al[sr * 32 + sc] = ga0;
    *(short8*)&Al[(64 + sr) * 32 + sc] = ga1;
    *(short8*)&Bl[sr * 32 + sc] = gb0;
    *(short8*)&Bl[(64 + sr) * 32 + sc] = gb1;
    __syncthreads();
    short8 a[4], b[4];
#pragma unroll
    for (int i = 0; i < 4; i++)
      a[i] = *(const short8*)&Al[(wm + i * 16 + (lane & 15)) * 32 + (lane >> 4) * 8];
#pragma unroll
    for (int j = 0; j < 4; j++)
      b[j] = *(const short8*)&Bl[(wn + j * 16 + (lane & 15)) * 32 + (lane >> 4) * 8];
#pragma unroll
    for (int i = 0; i < 4; i++)
#pragma unroll
      for (int j = 0; j < 4; j++)
        acc[i][j] = __builtin_amdgcn_mfma_f32_16x16x32_bf16(a[i], b[j], acc[i][j], 0, 0, 0);
    __syncthreads();
  }
#pragma unroll
  for (int j = 0; j < 4; j++) {
    int n = n0 + wn + j * 16 + (lane & 15);
    float bias = bo[n];
#pragma unroll
    for (int i = 0; i < 4; i++)
#pragma unroll
      for (int r = 0; r < 4; r++) {
        int m = m0 + wm + i * 16 + (lane >> 4) * 4 + r;
        out[(size_t)m * 2048 + n] = acc[i][j][r] + bias;
      }
  }
}

extern "C" void kernel_launch(void* const* d_in, const int* in_sizes, int n_in,
                              void* d_out, int out_size, void* d_ws, size_t ws_size,
                              hipStream_t stream) {
  const float* x  = (const float*)d_in[0];
  const float* wq = (const float*)d_in[1];
  const float* bq = (const float*)d_in[2];
  const float* wk = (const float*)d_in[3];
  const float* bk = (const float*)d_in[4];
  const float* wv = (const float*)d_in[5];
  const float* bv = (const float*)d_in[6];
  const float* wo = (const float*)d_in[7];
  const float* bo = (const float*)d_in[8];
  float* out = (float*)d_out;  // f32 output per reference dtype

  // bf16 workspace, ~63 MB total
  short* W1t = (short*)d_ws;                    // 3072*2048
  short* Wot = W1t + (size_t)3072 * 2048;       // 2048*2048
  short* qb_ = Wot + (size_t)2048 * 2048;       // 4096*2048
  short* kb_ = qb_ + (size_t)4096 * 2048;       // 2*4*2048*128
  short* vt_ = kb_ + (size_t)4096 * 512;        // 2*4*128*2048
  short* ao_ = vt_ + (size_t)4096 * 512;        // 4096*2048

  dim3 tb(32, 8);
  transpose_f2b<<<dim3(64, 64), tb, 0, stream>>>(wq, W1t, 2048, 2048);
  transpose_f2b<<<dim3(16, 64), tb, 0, stream>>>(wk, W1t + (size_t)2048 * 2048, 2048, 512);
  transpose_f2b<<<dim3(16, 64), tb, 0, stream>>>(wv, W1t + (size_t)2560 * 2048, 2048, 512);
  transpose_f2b<<<dim3(64, 64), tb, 0, stream>>>(wo, Wot, 2048, 2048);

  gemm_qkv<<<dim3(32, 24), 256, 0, stream>>>(x, W1t, bq, bk, bv, qb_, kb_, vt_);
  attn_kernel<<<dim3(32, 16, 2), 256, 0, stream>>>(qb_, kb_, vt_, ao_);
  gemm_out<<<dim3(32, 16), 256, 0, stream>>>(ao_, Wot, bo, out);
}

// Round 5
// 1200.462 us; speedup vs baseline: 1.1151x; 1.1151x over previous
//
#include <hip/hip_runtime.h>
#include <math.h>

// Problem constants
#define BB 2
#define SS 2048
#define EE 2048
#define HH 16
#define KVH 4
#define HD 128

typedef __attribute__((ext_vector_type(8))) short short8;
typedef __attribute__((ext_vector_type(4))) float f32x4;

__device__ __forceinline__ short f2b(float f) {
  unsigned u = __float_as_uint(f);
  unsigned r = (u + 0x7fffu + ((u >> 16) & 1u)) >> 16;
  return (short)r;
}

__device__ __forceinline__ void async_load16(const void* g, void* l) {
  __builtin_amdgcn_global_load_lds(
      (const __attribute__((address_space(1))) void*)g,
      (__attribute__((address_space(3))) void*)l, 16, 0, 0);
}

// RoPE freq replicating reference fp32 overflow: freqs[jp] = 1/theta^(2jp);
// theta^8 -> inf -> 0 (exp2f underflows likewise).
__device__ __forceinline__ float rope_freq(int jp) {
  return exp2f(-(float)(2 * jp) * 16.609640474436812f);
}

// ---------------- x: f32 -> bf16, elementwise ----------------
__global__ void f32_to_bf16(const float* __restrict__ in, short* __restrict__ out) {
  int i = (blockIdx.x * 256 + threadIdx.x) * 8;
  float4 a = *(const float4*)(in + i);
  float4 b = *(const float4*)(in + i + 4);
  short8 c;
  c[0] = f2b(a.x); c[1] = f2b(a.y); c[2] = f2b(a.z); c[3] = f2b(a.w);
  c[4] = f2b(b.x); c[5] = f2b(b.y); c[6] = f2b(b.z); c[7] = f2b(b.w);
  *(short8*)(out + i) = c;
}

// ---------------- weight transpose + f32->bf16: (K,N) f32 -> (N,K) bf16 ----
__global__ void transpose_f2b(const float* __restrict__ in, short* __restrict__ out,
                              int K, int N) {
  __shared__ short tile[32][33];
  int n0 = blockIdx.x * 32, k0 = blockIdx.y * 32;
  int tx = threadIdx.x, ty = threadIdx.y;  // 32 x 8
#pragma unroll
  for (int i = 0; i < 32; i += 8)
    tile[ty + i][tx] = f2b(in[(size_t)(k0 + ty + i) * N + n0 + tx]);
  __syncthreads();
#pragma unroll
  for (int i = 0; i < 32; i += 8)
    out[(size_t)(n0 + ty + i) * K + k0 + tx] = tile[tx][ty + i];
}

// -------------------- QKV GEMM + bias + RoPE --------------------
// A: xb (4096 x 2048) bf16. Bt: packed bf16 [wq^T; wk^T; wv^T] (3072 x 2048).
// 128x128 tile, 4 waves (2x2 of 64x64), K-step 32, mfma 16x16x32 bf16.
// Staging via global_load_lds(16B); epilogue staged through LDS for coalesced
// full-line HBM writes (was: 2B scatter -> 2.9GB write amplification).
__global__ __launch_bounds__(256) void gemm_qkv(
    const short* __restrict__ A, const short* __restrict__ Bt,
    const float* __restrict__ bq, const float* __restrict__ bk,
    const float* __restrict__ bv,
    short* __restrict__ qbuf, short* __restrict__ kbuf, short* __restrict__ vtr) {
  __shared__ __align__(16) short Sm[128 * 136];  // 34816 B; K-loop uses first 16KB
  short* Al = Sm;
  short* Bl = Sm + 128 * 32;
  const int K = EE;
  int t = threadIdx.x, lane = t & 63, w = t >> 6;
  int wm = (w >> 1) * 64, wn = (w & 1) * 64;
  int m0 = blockIdx.x * 128, n0 = blockIdx.y * 128;
  const short* Ab = A + (size_t)m0 * K;
  const short* Bb = Bt + (size_t)n0 * K;
  int sr = t >> 2, sc = (t & 3) * 8;  // 4 lanes per 32-short row
  char* AlB = (char*)Al + w * 1024;   // wave-uniform LDS base (lane*16 scatter)
  char* BlB = (char*)Bl + w * 1024;
  f32x4 acc[4][4] = {};
  for (int k0 = 0; k0 < K; k0 += 32) {
    async_load16(Ab + (size_t)sr * K + k0 + sc, AlB);
    async_load16(Ab + (size_t)(64 + sr) * K + k0 + sc, AlB + 4096);
    async_load16(Bb + (size_t)sr * K + k0 + sc, BlB);
    async_load16(Bb + (size_t)(64 + sr) * K + k0 + sc, BlB + 4096);
    __syncthreads();
    short8 a[4], b[4];
#pragma unroll
    for (int i = 0; i < 4; i++)
      a[i] = *(const short8*)&Al[(wm + i * 16 + (lane & 15)) * 32 + (lane >> 4) * 8];
#pragma unroll
    for (int j = 0; j < 4; j++)
      b[j] = *(const short8*)&Bl[(wn + j * 16 + (lane & 15)) * 32 + (lane >> 4) * 8];
#pragma unroll
    for (int i = 0; i < 4; i++)
#pragma unroll
      for (int j = 0; j < 4; j++)
        acc[i][j] = __builtin_amdgcn_mfma_f32_16x16x32_bf16(a[i], b[j], acc[i][j], 0, 0, 0);
    __syncthreads();
  }
  int lj = lane & 15, lr = lane >> 4;
  // ---- stage epilogue tile into LDS (pitch 136 breaks bank alignment) ----
  if (n0 < 2048) {  // Q: bias + rope, row-major (s_loc, d)
#pragma unroll
    for (int j = 0; j < 4; j++) {
      int d = wn + j * 16 + lj;
      float bias = bq[n0 + d];
      float freq = rope_freq(d >> 1);
      bool odd = (d & 1) != 0;
#pragma unroll
      for (int i = 0; i < 4; i++)
#pragma unroll
        for (int r = 0; r < 4; r++) {
          int mloc = wm + i * 16 + lr * 4 + r;
          int s = (m0 + mloc) & (SS - 1);
          float val = acc[i][j][r] + bias;
          float other = __shfl_xor(val, 1, 64);
          float ang = (float)s * freq;
          float cs = cosf(ang), sn = sinf(ang);
          float res = odd ? (other * sn + val * cs) : (val * cs - other * sn);
          Sm[mloc * 136 + d] = f2b(res);
        }
    }
  } else if (n0 < 2560) {  // K: bias + rope, row-major (s_loc, d)
    int base = n0 - 2048;
#pragma unroll
    for (int j = 0; j < 4; j++) {
      int d = wn + j * 16 + lj;
      float bias = bk[base + d];
      float freq = rope_freq(d >> 1);
      bool odd = (d & 1) != 0;
#pragma unroll
      for (int i = 0; i < 4; i++)
#pragma unroll
        for (int r = 0; r < 4; r++) {
          int mloc = wm + i * 16 + lr * 4 + r;
          int s = (m0 + mloc) & (SS - 1);
          float val = acc[i][j][r] + bias;
          float other = __shfl_xor(val, 1, 64);
          float ang = (float)s * freq;
          float cs = cosf(ang), sn = sinf(ang);
          float res = odd ? (other * sn + val * cs) : (val * cs - other * sn);
          Sm[mloc * 136 + d] = f2b(res);
        }
    }
  } else {  // V: bias, stage TRANSPOSED (d, s_loc)
    int base = n0 - 2560;
#pragma unroll
    for (int j = 0; j < 4; j++) {
      int d = wn + j * 16 + lj;
      float bias = bv[base + d];
#pragma unroll
      for (int i = 0; i < 4; i++)
#pragma unroll
        for (int r = 0; r < 4; r++) {
          int mloc = wm + i * 16 + lr * 4 + r;
          Sm[d * 136 + mloc] = f2b(acc[i][j][r] + bias);
        }
    }
  }
  __syncthreads();
  // ---- coalesced write-out: 16 rows/pass x 8 passes, 256B per row ----
  int r0 = t >> 4, ch = t & 15;
  if (n0 < 2048) {
#pragma unroll
    for (int p = 0; p < 8; p++) {
      int row = p * 16 + r0;  // s_loc
      *(short8*)(qbuf + (size_t)(m0 + row) * 2048 + n0 + ch * 8) =
          *(const short8*)&Sm[row * 136 + ch * 8];
    }
  } else if (n0 < 2560) {
    int kvh = (n0 - 2048) >> 7;
    int b = m0 >> 11, s0 = m0 & (SS - 1);
    short* dst = kbuf + ((size_t)(b * KVH + kvh) * SS + s0) * HD;
#pragma unroll
    for (int p = 0; p < 8; p++) {
      int row = p * 16 + r0;  // s_loc
      *(short8*)(dst + (size_t)row * HD + ch * 8) = *(const short8*)&Sm[row * 136 + ch * 8];
    }
  } else {
    int kvh = (n0 - 2560) >> 7;
    int b = m0 >> 11, s0 = m0 & (SS - 1);
    short* dst = vtr + ((size_t)(b * KVH + kvh) * HD) * SS + s0;
#pragma unroll
    for (int p = 0; p < 8; p++) {
      int row = p * 16 + r0;  // d
      *(short8*)(dst + (size_t)row * SS + ch * 8) = *(const short8*)&Sm[row * 136 + ch * 8];
    }
  }
}

// -------------------- flash attention (causal, GQA) --------------------
__global__ __launch_bounds__(256) void attn_kernel(
    const short* __restrict__ qb, const short* __restrict__ kb,
    const short* __restrict__ vt, short* __restrict__ ao) {
  __shared__ __align__(16) short Kl[64 * 128];     // (key, hd)
  __shared__ __align__(16) short Vl[128 * 64];     // (hd, key)
  __shared__ __align__(16) short Pl[4 * 16 * 64];  // per-wave P
  int t = threadIdx.x, lane = t & 63, w = t >> 6;
  int lj = lane & 15, lr = lane >> 4;
  int qt = blockIdx.x, h = blockIdx.y, b = blockIdx.z;
  int kvh = h >> 2;  // REP = 4
  int qb0 = qt * 64;
  const short* qbase = qb + (size_t)(b * SS) * 2048 + h * HD;
  const short* kbase = kb + (size_t)(b * KVH + kvh) * SS * HD;
  const short* vbase = vt + (size_t)(b * KVH + kvh) * HD * SS;
  short8 aq[4];
  int sq = qb0 + w * 16 + lj;
#pragma unroll
  for (int kk = 0; kk < 4; kk++)
    aq[kk] = *(const short8*)(qbase + (size_t)sq * 2048 + kk * 32 + lr * 8);
  f32x4 O[8] = {};
  const float NEG = -1e30f;
  float mrow[4] = {NEG, NEG, NEG, NEG};
  float lrow[4] = {0.f, 0.f, 0.f, 0.f};
  const float scale = 0.088388347648318447f;  // 1/sqrt(128)
  int nkt = qt + 1;
  for (int kt = 0; kt < nkt; ++kt) {
    short8 gk[4], gv[4];
#pragma unroll
    for (int i = 0; i < 4; i++) {
      gk[i] = *(const short8*)(kbase + (size_t)(kt * 64 + i * 16 + (t >> 4)) * HD + (t & 15) * 8);
      gv[i] = *(const short8*)(vbase + (size_t)(i * 32 + (t >> 3)) * SS + kt * 64 + (t & 7) * 8);
    }
#pragma unroll
    for (int i = 0; i < 4; i++) {
      *(short8*)&Kl[(i * 16 + (t >> 4)) * 128 + (t & 15) * 8] = gk[i];
      *(short8*)&Vl[(i * 32 + (t >> 3)) * 64 + (t & 7) * 8] = gv[i];
    }
    __syncthreads();
    f32x4 S[4];
#pragma unroll
    for (int nt = 0; nt < 4; nt++) {
      f32x4 sc = {};
#pragma unroll
      for (int kk = 0; kk < 4; kk++) {
        short8 bk_ = *(const short8*)&Kl[(nt * 16 + lj) * 128 + kk * 32 + lr * 8];
        sc = __builtin_amdgcn_mfma_f32_16x16x32_bf16(aq[kk], bk_, sc, 0, 0, 0);
      }
      S[nt] = sc;
    }
    int rowg = qb0 + w * 16 + lr * 4;
#pragma unroll
    for (int nt = 0; nt < 4; nt++) {
      int colg = kt * 64 + nt * 16 + lj;
#pragma unroll
      for (int r = 0; r < 4; r++) {
        float v = S[nt][r] * scale;
        if (colg > rowg + r) v = NEG;  // finite mask; exp underflows to 0
        S[nt][r] = v;
      }
    }
    float alpha[4];
#pragma unroll
    for (int r = 0; r < 4; r++) {
      float m_ = fmaxf(fmaxf(S[0][r], S[1][r]), fmaxf(S[2][r], S[3][r]));
#pragma unroll
      for (int off = 1; off < 16; off <<= 1) m_ = fmaxf(m_, __shfl_xor(m_, off, 64));
      float mn = fmaxf(mrow[r], m_);
      alpha[r] = __expf(mrow[r] - mn);
      mrow[r] = mn;
    }
    float ls[4] = {0.f, 0.f, 0.f, 0.f};
#pragma unroll
    for (int nt = 0; nt < 4; nt++)
#pragma unroll
      for (int r = 0; r < 4; r++) {
        float p = __expf(S[nt][r] - mrow[r]);
        ls[r] += p;
        Pl[(w * 16 + lr * 4 + r) * 64 + nt * 16 + lj] = f2b(p);
      }
#pragma unroll
    for (int r = 0; r < 4; r++) {
      float s_ = ls[r];
#pragma unroll
      for (int off = 1; off < 16; off <<= 1) s_ += __shfl_xor(s_, off, 64);
      lrow[r] = lrow[r] * alpha[r] + s_;
    }
#pragma unroll
    for (int jt = 0; jt < 8; jt++)
#pragma unroll
      for (int r = 0; r < 4; r++) O[jt][r] *= alpha[r];
#pragma unroll
    for (int kk = 0; kk < 2; kk++) {
      short8 ap = *(const short8*)&Pl[(w * 16 + lj) * 64 + kk * 32 + lr * 8];
#pragma unroll
      for (int jt = 0; jt < 8; jt++) {
        short8 bv_ = *(const short8*)&Vl[(jt * 16 + lj) * 64 + kk * 32 + lr * 8];
        O[jt] = __builtin_amdgcn_mfma_f32_16x16x32_bf16(ap, bv_, O[jt], 0, 0, 0);
      }
    }
    __syncthreads();
  }
  size_t obase = (size_t)(b * SS + qb0 + w * 16) * 2048 + h * HD;
#pragma unroll
  for (int jt = 0; jt < 8; jt++)
#pragma unroll
    for (int r = 0; r < 4; r++) {
      int row = lr * 4 + r;
      ao[obase + (size_t)row * 2048 + jt * 16 + lj] = f2b(O[jt][r] / lrow[r]);
    }
}

// -------------- output projection GEMM + bias (f32 output) --------------
__global__ __launch_bounds__(256) void gemm_out(
    const short* __restrict__ A, const short* __restrict__ Bt,
    const float* __restrict__ bo, float* __restrict__ out) {
  __shared__ __align__(16) short Al[128 * 32];
  __shared__ __align__(16) short Bl[128 * 32];
  const int K = EE;
  int t = threadIdx.x, lane = t & 63, w = t >> 6;
  int wm = (w >> 1) * 64, wn = (w & 1) * 64;
  int m0 = blockIdx.x * 128, n0 = blockIdx.y * 128;
  const short* Ab = A + (size_t)m0 * K;
  const short* Bb = Bt + (size_t)n0 * K;
  int sr = t >> 2, sc = (t & 3) * 8;
  char* AlB = (char*)Al + w * 1024;
  char* BlB = (char*)Bl + w * 1024;
  f32x4 acc[4][4] = {};
  for (int k0 = 0; k0 < K; k0 += 32) {
    async_load16(Ab + (size_t)sr * K + k0 + sc, AlB);
    async_load16(Ab + (size_t)(64 + sr) * K + k0 + sc, AlB + 4096);
    async_load16(Bb + (size_t)sr * K + k0 + sc, BlB);
    async_load16(Bb + (size_t)(64 + sr) * K + k0 + sc, BlB + 4096);
    __syncthreads();
    short8 a[4], b[4];
#pragma unroll
    for (int i = 0; i < 4; i++)
      a[i] = *(const short8*)&Al[(wm + i * 16 + (lane & 15)) * 32 + (lane >> 4) * 8];
#pragma unroll
    for (int j = 0; j < 4; j++)
      b[j] = *(const short8*)&Bl[(wn + j * 16 + (lane & 15)) * 32 + (lane >> 4) * 8];
#pragma unroll
    for (int i = 0; i < 4; i++)
#pragma unroll
      for (int j = 0; j < 4; j++)
        acc[i][j] = __builtin_amdgcn_mfma_f32_16x16x32_bf16(a[i], b[j], acc[i][j], 0, 0, 0);
    __syncthreads();
  }
#pragma unroll
  for (int j = 0; j < 4; j++) {
    int n = n0 + wn + j * 16 + (lane & 15);
    float bias = bo[n];
#pragma unroll
    for (int i = 0; i < 4; i++)
#pragma unroll
      for (int r = 0; r < 4; r++) {
        int m = m0 + wm + i * 16 + (lane >> 4) * 4 + r;
        out[(size_t)m * 2048 + n] = acc[i][j][r] + bias;
      }
  }
}

extern "C" void kernel_launch(void* const* d_in, const int* in_sizes, int n_in,
                              void* d_out, int out_size, void* d_ws, size_t ws_size,
                              hipStream_t stream) {
  const float* x  = (const float*)d_in[0];
  const float* wq = (const float*)d_in[1];
  const float* bq = (const float*)d_in[2];
  const float* wk = (const float*)d_in[3];
  const float* bk = (const float*)d_in[4];
  const float* wv = (const float*)d_in[5];
  const float* bv = (const float*)d_in[6];
  const float* wo = (const float*)d_in[7];
  const float* bo = (const float*)d_in[8];
  float* out = (float*)d_out;  // f32 output per reference dtype

  // bf16 workspace, ~63 MB total. xb_ aliases ao_: xb_ is consumed by
  // gemm_qkv before attn writes ao_ (stream-ordered).
  short* W1t = (short*)d_ws;                    // 3072*2048
  short* Wot = W1t + (size_t)3072 * 2048;       // 2048*2048
  short* qb_ = Wot + (size_t)2048 * 2048;       // 4096*2048
  short* kb_ = qb_ + (size_t)4096 * 2048;       // 2*4*2048*128
  short* vt_ = kb_ + (size_t)4096 * 512;        // 2*4*128*2048
  short* ao_ = vt_ + (size_t)4096 * 512;        // 4096*2048
  short* xb_ = ao_;                             // alias (disjoint lifetime)

  dim3 tb(32, 8);
  f32_to_bf16<<<4096, 256, 0, stream>>>(x, xb_);
  transpose_f2b<<<dim3(64, 64), tb, 0, stream>>>(wq, W1t, 2048, 2048);
  transpose_f2b<<<dim3(16, 64), tb, 0, stream>>>(wk, W1t + (size_t)2048 * 2048, 2048, 512);
  transpose_f2b<<<dim3(16, 64), tb, 0, stream>>>(wv, W1t + (size_t)2560 * 2048, 2048, 512);
  transpose_f2b<<<dim3(64, 64), tb, 0, stream>>>(wo, Wot, 2048, 2048);

  gemm_qkv<<<dim3(32, 24), 256, 0, stream>>>(xb_, W1t, bq, bk, bv, qb_, kb_, vt_);
  attn_kernel<<<dim3(32, 16, 2), 256, 0, stream>>>(qb_, kb_, vt_, ao_);
  gemm_out<<<dim3(32, 16), 256, 0, stream>>>(ao_, Wot, bo, out);
}

// Round 6
// 944.162 us; speedup vs baseline: 1.4178x; 1.2715x over previous
//
#include <hip/hip_runtime.h>
#include <math.h>

// Problem constants
#define BB 2
#define SS 2048
#define EE 2048
#define HH 16
#define KVH 4
#define HD 128

typedef __attribute__((ext_vector_type(8))) short short8;
typedef __attribute__((ext_vector_type(4))) float f32x4;

__device__ __forceinline__ short f2b(float f) {
  unsigned u = __float_as_uint(f);
  unsigned r = (u + 0x7fffu + ((u >> 16) & 1u)) >> 16;
  return (short)r;
}

__device__ __forceinline__ void async_load16(const void* g, void* l) {
  __builtin_amdgcn_global_load_lds(
      (const __attribute__((address_space(1))) void*)g,
      (__attribute__((address_space(3))) void*)l, 16, 0, 0);
}

// RoPE freq replicating reference fp32 overflow: freqs[jp] = 1/theta^(2jp);
// theta^8 -> inf -> 0 (exp2f underflows likewise).
__device__ __forceinline__ float rope_freq(int jp) {
  return exp2f(-(float)(2 * jp) * 16.609640474436812f);
}

// ---------------- x: f32 -> bf16, elementwise ----------------
__global__ void f32_to_bf16(const float* __restrict__ in, short* __restrict__ out) {
  int i = (blockIdx.x * 256 + threadIdx.x) * 8;
  float4 a = *(const float4*)(in + i);
  float4 b = *(const float4*)(in + i + 4);
  short8 c;
  c[0] = f2b(a.x); c[1] = f2b(a.y); c[2] = f2b(a.z); c[3] = f2b(a.w);
  c[4] = f2b(b.x); c[5] = f2b(b.y); c[6] = f2b(b.z); c[7] = f2b(b.w);
  *(short8*)(out + i) = c;
}

// ---------------- weight transpose + f32->bf16: (K,N) f32 -> (N,K) bf16 ----
__global__ void transpose_f2b(const float* __restrict__ in, short* __restrict__ out,
                              int K, int N) {
  __shared__ short tile[32][33];
  int n0 = blockIdx.x * 32, k0 = blockIdx.y * 32;
  int tx = threadIdx.x, ty = threadIdx.y;  // 32 x 8
#pragma unroll
  for (int i = 0; i < 32; i += 8)
    tile[ty + i][tx] = f2b(in[(size_t)(k0 + ty + i) * N + n0 + tx]);
  __syncthreads();
#pragma unroll
  for (int i = 0; i < 32; i += 8)
    out[(size_t)(n0 + ty + i) * K + k0 + tx] = tile[tx][ty + i];
}

// -------------------- QKV GEMM + bias + RoPE --------------------
// A: xb (4096 x 2048) bf16. Bt: packed bf16 [wq^T; wk^T; wv^T] (3072 x 2048).
// 128x128 tile, 4 waves (2x2 of 64x64), BK=64 (two mfma k-steps per barrier;
// 8 global_load_lds in flight per iter -> latency tolerance under HBM
// contention from harness restore/poison background traffic).
__global__ __launch_bounds__(256) void gemm_qkv(
    const short* __restrict__ A, const short* __restrict__ Bt,
    const float* __restrict__ bq, const float* __restrict__ bk,
    const float* __restrict__ bv,
    short* __restrict__ qbuf, short* __restrict__ kbuf, short* __restrict__ vtr) {
  __shared__ __align__(16) short Sm[128 * 136];  // 34816 B; K-loop uses 32 KB
  short* Al = Sm;             // 128 x 64 bf16
  short* Bl = Sm + 128 * 64;  // 128 x 64 bf16
  const int K = EE;
  int t = threadIdx.x, lane = t & 63, w = t >> 6;
  int wm = (w >> 1) * 64, wn = (w & 1) * 64;
  int m0 = blockIdx.x * 128, n0 = blockIdx.y * 128;
  const short* Ab = A + (size_t)m0 * K;
  const short* Bb = Bt + (size_t)n0 * K;
  // staging: issue q covers rows q*32+(t>>3), cols (t&7)*8 (8 lanes = 128 B row seg)
  int srow = t >> 3, scol = (t & 7) * 8;
  int lj = lane & 15, lr = lane >> 4;
  f32x4 acc[4][4] = {};
  for (int k0 = 0; k0 < K; k0 += 64) {
#pragma unroll
    for (int q = 0; q < 4; q++) {
      async_load16(Ab + (size_t)(q * 32 + srow) * K + k0 + scol,
                   (char*)Al + q * 4096 + w * 1024);
      async_load16(Bb + (size_t)(q * 32 + srow) * K + k0 + scol,
                   (char*)Bl + q * 4096 + w * 1024);
    }
    __syncthreads();
    short8 a0[4], a1[4], b0[4], b1[4];
#pragma unroll
    for (int i = 0; i < 4; i++) {
      a0[i] = *(const short8*)&Al[(wm + i * 16 + lj) * 64 + lr * 8];
      a1[i] = *(const short8*)&Al[(wm + i * 16 + lj) * 64 + 32 + lr * 8];
    }
#pragma unroll
    for (int j = 0; j < 4; j++) {
      b0[j] = *(const short8*)&Bl[(wn + j * 16 + lj) * 64 + lr * 8];
      b1[j] = *(const short8*)&Bl[(wn + j * 16 + lj) * 64 + 32 + lr * 8];
    }
#pragma unroll
    for (int i = 0; i < 4; i++)
#pragma unroll
      for (int j = 0; j < 4; j++) {
        acc[i][j] = __builtin_amdgcn_mfma_f32_16x16x32_bf16(a0[i], b0[j], acc[i][j], 0, 0, 0);
        acc[i][j] = __builtin_amdgcn_mfma_f32_16x16x32_bf16(a1[i], b1[j], acc[i][j], 0, 0, 0);
      }
    __syncthreads();
  }
  // ---- stage epilogue tile into LDS (pitch 136), then coalesced write ----
  if (n0 < 2048) {  // Q: bias + rope, row-major (s_loc, d)
#pragma unroll
    for (int j = 0; j < 4; j++) {
      int d = wn + j * 16 + lj;
      float bias = bq[n0 + d];
      float freq = rope_freq(d >> 1);
      bool odd = (d & 1) != 0;
#pragma unroll
      for (int i = 0; i < 4; i++)
#pragma unroll
        for (int r = 0; r < 4; r++) {
          int mloc = wm + i * 16 + lr * 4 + r;
          int s = (m0 + mloc) & (SS - 1);
          float val = acc[i][j][r] + bias;
          float other = __shfl_xor(val, 1, 64);
          float ang = (float)s * freq;
          float cs = cosf(ang), sn = sinf(ang);
          float res = odd ? (other * sn + val * cs) : (val * cs - other * sn);
          Sm[mloc * 136 + d] = f2b(res);
        }
    }
  } else if (n0 < 2560) {  // K: bias + rope, row-major (s_loc, d)
    int base = n0 - 2048;
#pragma unroll
    for (int j = 0; j < 4; j++) {
      int d = wn + j * 16 + lj;
      float bias = bk[base + d];
      float freq = rope_freq(d >> 1);
      bool odd = (d & 1) != 0;
#pragma unroll
      for (int i = 0; i < 4; i++)
#pragma unroll
        for (int r = 0; r < 4; r++) {
          int mloc = wm + i * 16 + lr * 4 + r;
          int s = (m0 + mloc) & (SS - 1);
          float val = acc[i][j][r] + bias;
          float other = __shfl_xor(val, 1, 64);
          float ang = (float)s * freq;
          float cs = cosf(ang), sn = sinf(ang);
          float res = odd ? (other * sn + val * cs) : (val * cs - other * sn);
          Sm[mloc * 136 + d] = f2b(res);
        }
    }
  } else {  // V: bias, stage TRANSPOSED (d, s_loc)
    int base = n0 - 2560;
#pragma unroll
    for (int j = 0; j < 4; j++) {
      int d = wn + j * 16 + lj;
      float bias = bv[base + d];
#pragma unroll
      for (int i = 0; i < 4; i++)
#pragma unroll
        for (int r = 0; r < 4; r++) {
          int mloc = wm + i * 16 + lr * 4 + r;
          Sm[d * 136 + mloc] = f2b(acc[i][j][r] + bias);
        }
    }
  }
  __syncthreads();
  int r0 = t >> 4, ch = t & 15;
  if (n0 < 2048) {
#pragma unroll
    for (int p = 0; p < 8; p++) {
      int row = p * 16 + r0;  // s_loc
      *(short8*)(qbuf + (size_t)(m0 + row) * 2048 + n0 + ch * 8) =
          *(const short8*)&Sm[row * 136 + ch * 8];
    }
  } else if (n0 < 2560) {
    int kvh = (n0 - 2048) >> 7;
    int b = m0 >> 11, s0 = m0 & (SS - 1);
    short* dst = kbuf + ((size_t)(b * KVH + kvh) * SS + s0) * HD;
#pragma unroll
    for (int p = 0; p < 8; p++) {
      int row = p * 16 + r0;  // s_loc
      *(short8*)(dst + (size_t)row * HD + ch * 8) = *(const short8*)&Sm[row * 136 + ch * 8];
    }
  } else {
    int kvh = (n0 - 2560) >> 7;
    int b = m0 >> 11, s0 = m0 & (SS - 1);
    short* dst = vtr + ((size_t)(b * KVH + kvh) * HD) * SS + s0;
#pragma unroll
    for (int p = 0; p < 8; p++) {
      int row = p * 16 + r0;  // d
      *(short8*)(dst + (size_t)row * SS + ch * 8) = *(const short8*)&Sm[row * 136 + ch * 8];
    }
  }
}

// -------------------- flash attention (causal, GQA) --------------------
__global__ __launch_bounds__(256) void attn_kernel(
    const short* __restrict__ qb, const short* __restrict__ kb,
    const short* __restrict__ vt, short* __restrict__ ao) {
  __shared__ __align__(16) short Kl[64 * 128];     // (key, hd)
  __shared__ __align__(16) short Vl[128 * 64];     // (hd, key)
  __shared__ __align__(16) short Pl[4 * 16 * 64];  // per-wave P
  int t = threadIdx.x, lane = t & 63, w = t >> 6;
  int lj = lane & 15, lr = lane >> 4;
  int qt = blockIdx.x, h = blockIdx.y, b = blockIdx.z;
  int kvh = h >> 2;  // REP = 4
  int qb0 = qt * 64;
  const short* qbase = qb + (size_t)(b * SS) * 2048 + h * HD;
  const short* kbase = kb + (size_t)(b * KVH + kvh) * SS * HD;
  const short* vbase = vt + (size_t)(b * KVH + kvh) * HD * SS;
  short8 aq[4];
  int sq = qb0 + w * 16 + lj;
#pragma unroll
  for (int kk = 0; kk < 4; kk++)
    aq[kk] = *(const short8*)(qbase + (size_t)sq * 2048 + kk * 32 + lr * 8);
  f32x4 O[8] = {};
  const float NEG = -1e30f;
  float mrow[4] = {NEG, NEG, NEG, NEG};
  float lrow[4] = {0.f, 0.f, 0.f, 0.f};
  const float scale = 0.088388347648318447f;  // 1/sqrt(128)
  int nkt = qt + 1;
  for (int kt = 0; kt < nkt; ++kt) {
    short8 gk[4], gv[4];
#pragma unroll
    for (int i = 0; i < 4; i++) {
      gk[i] = *(const short8*)(kbase + (size_t)(kt * 64 + i * 16 + (t >> 4)) * HD + (t & 15) * 8);
      gv[i] = *(const short8*)(vbase + (size_t)(i * 32 + (t >> 3)) * SS + kt * 64 + (t & 7) * 8);
    }
#pragma unroll
    for (int i = 0; i < 4; i++) {
      *(short8*)&Kl[(i * 16 + (t >> 4)) * 128 + (t & 15) * 8] = gk[i];
      *(short8*)&Vl[(i * 32 + (t >> 3)) * 64 + (t & 7) * 8] = gv[i];
    }
    __syncthreads();
    f32x4 S[4];
#pragma unroll
    for (int nt = 0; nt < 4; nt++) {
      f32x4 sc = {};
#pragma unroll
      for (int kk = 0; kk < 4; kk++) {
        short8 bk_ = *(const short8*)&Kl[(nt * 16 + lj) * 128 + kk * 32 + lr * 8];
        sc = __builtin_amdgcn_mfma_f32_16x16x32_bf16(aq[kk], bk_, sc, 0, 0, 0);
      }
      S[nt] = sc;
    }
    int rowg = qb0 + w * 16 + lr * 4;
#pragma unroll
    for (int nt = 0; nt < 4; nt++) {
      int colg = kt * 64 + nt * 16 + lj;
#pragma unroll
      for (int r = 0; r < 4; r++) {
        float v = S[nt][r] * scale;
        if (colg > rowg + r) v = NEG;  // finite mask; exp underflows to 0
        S[nt][r] = v;
      }
    }
    float alpha[4];
#pragma unroll
    for (int r = 0; r < 4; r++) {
      float m_ = fmaxf(fmaxf(S[0][r], S[1][r]), fmaxf(S[2][r], S[3][r]));
#pragma unroll
      for (int off = 1; off < 16; off <<= 1) m_ = fmaxf(m_, __shfl_xor(m_, off, 64));
      float mn = fmaxf(mrow[r], m_);
      alpha[r] = __expf(mrow[r] - mn);
      mrow[r] = mn;
    }
    float ls[4] = {0.f, 0.f, 0.f, 0.f};
#pragma unroll
    for (int nt = 0; nt < 4; nt++)
#pragma unroll
      for (int r = 0; r < 4; r++) {
        float p = __expf(S[nt][r] - mrow[r]);
        ls[r] += p;
        Pl[(w * 16 + lr * 4 + r) * 64 + nt * 16 + lj] = f2b(p);
      }
#pragma unroll
    for (int r = 0; r < 4; r++) {
      float s_ = ls[r];
#pragma unroll
      for (int off = 1; off < 16; off <<= 1) s_ += __shfl_xor(s_, off, 64);
      lrow[r] = lrow[r] * alpha[r] + s_;
    }
#pragma unroll
    for (int jt = 0; jt < 8; jt++)
#pragma unroll
      for (int r = 0; r < 4; r++) O[jt][r] *= alpha[r];
#pragma unroll
    for (int kk = 0; kk < 2; kk++) {
      short8 ap = *(const short8*)&Pl[(w * 16 + lj) * 64 + kk * 32 + lr * 8];
#pragma unroll
      for (int jt = 0; jt < 8; jt++) {
        short8 bv_ = *(const short8*)&Vl[(jt * 16 + lj) * 64 + kk * 32 + lr * 8];
        O[jt] = __builtin_amdgcn_mfma_f32_16x16x32_bf16(ap, bv_, O[jt], 0, 0, 0);
      }
    }
    __syncthreads();
  }
  size_t obase = (size_t)(b * SS + qb0 + w * 16) * 2048 + h * HD;
#pragma unroll
  for (int jt = 0; jt < 8; jt++)
#pragma unroll
    for (int r = 0; r < 4; r++) {
      int row = lr * 4 + r;
      ao[obase + (size_t)row * 2048 + jt * 16 + lj] = f2b(O[jt][r] / lrow[r]);
    }
}

// -------------- output projection GEMM + bias (f32 output) --------------
__global__ __launch_bounds__(256) void gemm_out(
    const short* __restrict__ A, const short* __restrict__ Bt,
    const float* __restrict__ bo, float* __restrict__ out) {
  __shared__ __align__(16) short Al[128 * 32];
  __shared__ __align__(16) short Bl[128 * 32];
  const int K = EE;
  int t = threadIdx.x, lane = t & 63, w = t >> 6;
  int wm = (w >> 1) * 64, wn = (w & 1) * 64;
  int m0 = blockIdx.x * 128, n0 = blockIdx.y * 128;
  const short* Ab = A + (size_t)m0 * K;
  const short* Bb = Bt + (size_t)n0 * K;
  int sr = t >> 2, sc = (t & 3) * 8;
  char* AlB = (char*)Al + w * 1024;
  char* BlB = (char*)Bl + w * 1024;
  f32x4 acc[4][4] = {};
  for (int k0 = 0; k0 < K; k0 += 32) {
    async_load16(Ab + (size_t)sr * K + k0 + sc, AlB);
    async_load16(Ab + (size_t)(64 + sr) * K + k0 + sc, AlB + 4096);
    async_load16(Bb + (size_t)sr * K + k0 + sc, BlB);
    async_load16(Bb + (size_t)(64 + sr) * K + k0 + sc, BlB + 4096);
    __syncthreads();
    short8 a[4], b[4];
#pragma unroll
    for (int i = 0; i < 4; i++)
      a[i] = *(const short8*)&Al[(wm + i * 16 + (lane & 15)) * 32 + (lane >> 4) * 8];
#pragma unroll
    for (int j = 0; j < 4; j++)
      b[j] = *(const short8*)&Bl[(wn + j * 16 + (lane & 15)) * 32 + (lane >> 4) * 8];
#pragma unroll
    for (int i = 0; i < 4; i++)
#pragma unroll
      for (int j = 0; j < 4; j++)
        acc[i][j] = __builtin_amdgcn_mfma_f32_16x16x32_bf16(a[i], b[j], acc[i][j], 0, 0, 0);
    __syncthreads();
  }
#pragma unroll
  for (int j = 0; j < 4; j++) {
    int n = n0 + wn + j * 16 + (lane & 15);
    float bias = bo[n];
#pragma unroll
    for (int i = 0; i < 4; i++)
#pragma unroll
      for (int r = 0; r < 4; r++) {
        int m = m0 + wm + i * 16 + (lane >> 4) * 4 + r;
        out[(size_t)m * 2048 + n] = acc[i][j][r] + bias;
      }
  }
}

extern "C" void kernel_launch(void* const* d_in, const int* in_sizes, int n_in,
                              void* d_out, int out_size, void* d_ws, size_t ws_size,
                              hipStream_t stream) {
  const float* x  = (const float*)d_in[0];
  const float* wq = (const float*)d_in[1];
  const float* bq = (const float*)d_in[2];
  const float* wk = (const float*)d_in[3];
  const float* bk = (const float*)d_in[4];
  const float* wv = (const float*)d_in[5];
  const float* bv = (const float*)d_in[6];
  const float* wo = (const float*)d_in[7];
  const float* bo = (const float*)d_in[8];
  float* out = (float*)d_out;  // f32 output per reference dtype

  // bf16 workspace, ~63 MB used. xb_ aliases ao_ (disjoint lifetime).
  short* W1t = (short*)d_ws;                    // 3072*2048
  short* Wot = W1t + (size_t)3072 * 2048;       // 2048*2048
  short* qb_ = Wot + (size_t)2048 * 2048;       // 4096*2048
  short* kb_ = qb_ + (size_t)4096 * 2048;       // 2*4*2048*128
  short* vt_ = kb_ + (size_t)4096 * 512;        // 2*4*128*2048
  short* ao_ = vt_ + (size_t)4096 * 512;        // 4096*2048
  short* xb_ = ao_;                             // alias (disjoint lifetime)

  dim3 tb(32, 8);
  f32_to_bf16<<<4096, 256, 0, stream>>>(x, xb_);
  transpose_f2b<<<dim3(64, 64), tb, 0, stream>>>(wq, W1t, 2048, 2048);
  transpose_f2b<<<dim3(16, 64), tb, 0, stream>>>(wk, W1t + (size_t)2048 * 2048, 2048, 512);
  transpose_f2b<<<dim3(16, 64), tb, 0, stream>>>(wv, W1t + (size_t)2560 * 2048, 2048, 512);
  transpose_f2b<<<dim3(64, 64), tb, 0, stream>>>(wo, Wot, 2048, 2048);

  gemm_qkv<<<dim3(32, 24), 256, 0, stream>>>(xb_, W1t, bq, bk, bv, qb_, kb_, vt_);
  attn_kernel<<<dim3(32, 16, 2), 256, 0, stream>>>(qb_, kb_, vt_, ao_);
  gemm_out<<<dim3(32, 16), 256, 0, stream>>>(ao_, Wot, bo, out);
}